// Round 2
// 4388.396 us; speedup vs baseline: 1.3571x; 1.3571x over previous
//
#include <hip/hip_runtime.h>

// RNN: x(128,512,1024) fp32, h0(128,1024), Wx(1024,1024), Wh(1024,1024), b(1024)
// out(128,512,1024) fp32.
// Phase 1: xp = x@Wx + b  -> written fp32 into d_out (in-place consumed later).
// Phase 2: persistent-RNN. 8 groups x 16 WGs; Wh fragments resident in VGPRs.
// Protocol v3: release publish (1 wbl2/step) + RELAXED poll (no inv per spin,
// ACQUIRE escalation every 64 spins for liveness) + ONE acquire fence per step
// (wave 0) before staging. Provably correct per C++/LLVM gfx950 memory model:
// no reliance on relaxed-atomic cache-bypass semantics (v2's deadlock risk).
// out stream is read-once/write-once -> nontemporal, keeps L2 clean so the
// per-step buffer_wbl2 is near-free.

#define NB   128
#define TT   512
#define DD   1024
#define HH   1024

typedef _Float16 half8 __attribute__((ext_vector_type(8)));
typedef float    f32x4 __attribute__((ext_vector_type(4)));

// ---------------------------------------------------------------- phase 1
__global__ __launch_bounds__(256, 2) void gemm_xp(
    const float* __restrict__ x, const float* __restrict__ Wx,
    const float* __restrict__ bias, float* __restrict__ out)
{
  const int tid = threadIdx.x;
  const int bid = blockIdx.x;
  const int bn  = bid & 7;       // 8 column blocks of 128 (consecutive bids share x tile -> L2)
  const int bm  = bid >> 3;      // 512 row blocks
  const int m0  = bm << 7, n0 = bn << 7;

  // fp16 tiles, row stride 40 halves (pad 8) -> 2-way-max bank aliasing (free)
  __shared__ _Float16 As[128 * 40];   // [m][k]
  __shared__ _Float16 Bs[128 * 40];   // [n][k]  (transposed Wx tile)

  const int w  = tid >> 6, lane = tid & 63;
  const int wm = (w >> 1) << 6, wn = (w & 1) << 6;   // 64x64 quadrant per wave
  const int lm = lane & 15, kq = lane >> 4;

  f32x4 acc[4][4] = {};

  for (int kb = 0; kb < 32; ++kb) {
    const int k0 = kb << 5;
    // stage A: 128 rows x 32 k, fp32 -> fp16
#pragma unroll
    for (int p = 0; p < 4; ++p) {
      int idx = p * 256 + tid;
      int r = idx >> 3, cb = idx & 7;
      float4 v = *(const float4*)(x + (size_t)(m0 + r) * DD + k0 + cb * 4);
      _Float16* d = &As[r * 40 + cb * 4];
      d[0] = (_Float16)v.x; d[1] = (_Float16)v.y;
      d[2] = (_Float16)v.z; d[3] = (_Float16)v.w;
    }
    // stage B transposed: 32 k x 128 n -> Bs[n][k]
#pragma unroll
    for (int p = 0; p < 4; ++p) {
      int idx = p * 256 + tid;
      int kk = idx >> 5, nb = idx & 31;
      float4 v = *(const float4*)(Wx + (size_t)(k0 + kk) * HH + n0 + nb * 4);
      Bs[(nb * 4 + 0) * 40 + kk] = (_Float16)v.x;
      Bs[(nb * 4 + 1) * 40 + kk] = (_Float16)v.y;
      Bs[(nb * 4 + 2) * 40 + kk] = (_Float16)v.z;
      Bs[(nb * 4 + 3) * 40 + kk] = (_Float16)v.w;
    }
    __syncthreads();
    half8 af[4], bf[4];
#pragma unroll
    for (int i = 0; i < 4; ++i)
      af[i] = *(const half8*)&As[(wm + i * 16 + lm) * 40 + kq * 8];
#pragma unroll
    for (int j = 0; j < 4; ++j)
      bf[j] = *(const half8*)&Bs[(wn + j * 16 + lm) * 40 + kq * 8];
#pragma unroll
    for (int i = 0; i < 4; ++i)
#pragma unroll
      for (int j = 0; j < 4; ++j)
        acc[i][j] = __builtin_amdgcn_mfma_f32_16x16x32_f16(af[i], bf[j], acc[i][j], 0, 0, 0);
    __syncthreads();
  }
  // epilogue: C/D layout col=lane&15, row=(lane>>4)*4+reg  [m89-verified]
#pragma unroll
  for (int i = 0; i < 4; ++i)
#pragma unroll
    for (int j = 0; j < 4; ++j) {
      int col = n0 + wn + j * 16 + lm;
      float bv = bias[col];
#pragma unroll
      for (int r = 0; r < 4; ++r) {
        int row = m0 + wm + i * 16 + kq * 4 + r;
        out[(size_t)row * HH + col] = acc[i][j][r] + bv;
      }
    }
}

// ---------------------------------------------------------------- phase 2
// grid = 128 blocks (8 groups x 16 WGs), 256 threads.
// group g owns batch rows [16g,16g+16); WG j owns columns [64j,64j+64).
// Wave w (16 cols) keeps Wh[k][cols] as 32 resident B-fragments (128 VGPRs).
__global__ __launch_bounds__(256, 1) void rnn_rec(
    const float* __restrict__ h0, const float* __restrict__ Wh,
    float* __restrict__ out,            // xp in, h out (in-place per element)
    _Float16* __restrict__ hbuf,        // [2][8][16][1024] fp16 ping-pong
    int* __restrict__ flags)            // [128 * 16] ints (64B-padded per WG)
{
  const int tid = threadIdx.x;
  const int b   = blockIdx.x;
  const int g   = b >> 4;           // group 0..7
  const int n0  = g << 4;           // first batch row of group
  const int c0  = (b & 15) << 6;    // first column of WG
  const int w   = tid >> 6, lane = tid & 63;
  const int cw  = c0 + (w << 4);    // wave's 16 columns
  const int lm  = lane & 15, kq = lane >> 4;

  __shared__ _Float16 hs[16 * 1032];  // h_t fp16, row stride 1032 (pad 8)

  // ---- load resident Wh B-fragments: B[k=kb*32+kq*8+jj][n=cw+lm]
  half8 bfrag[32];
#pragma unroll
  for (int kb = 0; kb < 32; ++kb) {
    half8 f;
#pragma unroll
    for (int jj = 0; jj < 8; ++jj) {
      int k = (kb << 5) + (kq << 3) + jj;
      f[jj] = (_Float16)Wh[(size_t)k * HH + cw + lm];
    }
    bfrag[kb] = f;
  }

  for (int t = 0; t < TT; ++t) {
    // issue xp loads early (independent of LDS staging; latency hidden by MFMA)
    // nontemporal: each xp line is read exactly once ever -> don't pollute L2.
    float xpv[4];
    size_t obase[4];
#pragma unroll
    for (int r = 0; r < 4; ++r) {
      int lr = (kq << 2) + r;                         // local row 0..15
      obase[r] = (size_t)(n0 + lr) * (TT * HH) + (size_t)t * HH + cw + lm;
      xpv[r] = __builtin_nontemporal_load(out + obase[r]);
    }

    // ---- stage h_t into LDS (fp16)
    if (t == 0) {
      // from h0 (fp32)
#pragma unroll
      for (int p = 0; p < 16; ++p) {
        float4 v = *(const float4*)(h0 + (size_t)(n0 + p) * HH + tid * 4);
        _Float16* d = &hs[p * 1032 + tid * 4];
        d[0] = (_Float16)v.x; d[1] = (_Float16)v.y;
        d[2] = (_Float16)v.z; d[3] = (_Float16)v.w;
      }
    } else {
      const _Float16* src = hbuf + ((size_t)(t & 1) * 8 + g) * (16 * 1024);
#pragma unroll
      for (int p = 0; p < 8; ++p) {
        int idx = (p << 11) + (tid << 3);
        int r = idx >> 10, c = idx & 1023;
        *(half8*)&hs[r * 1032 + c] = *(const half8*)(src + r * 1024 + c);
      }
    }
    __syncthreads();

    // ---- h_t @ Wh : A[m=lm][k=kb*32+kq*8+j] from LDS, B resident
    // two accumulators -> halve the dependent-MFMA chain
    f32x4 acc0 = {}, acc1 = {};
#pragma unroll
    for (int kb = 0; kb < 32; kb += 2) {
      half8 a0 = *(const half8*)&hs[lm * 1032 + (kb << 5) + (kq << 3)];
      half8 a1 = *(const half8*)&hs[lm * 1032 + ((kb + 1) << 5) + (kq << 3)];
      acc0 = __builtin_amdgcn_mfma_f32_16x16x32_f16(a0, bfrag[kb], acc0, 0, 0, 0);
      acc1 = __builtin_amdgcn_mfma_f32_16x16x32_f16(a1, bfrag[kb + 1], acc1, 0, 0, 0);
    }
    f32x4 acc = acc0 + acc1;

    // ---- epilogue: h = tanh(xp + acc); write d_out (fp32, nt) + ping (fp16)
    _Float16* ping = hbuf + ((size_t)((t + 1) & 1) * 8 + g) * (16 * 1024);
#pragma unroll
    for (int r = 0; r < 4; ++r) {
      int lr = (kq << 2) + r;
      float h = tanhf(acc[r] + xpv[r]);
      __builtin_nontemporal_store(h, out + obase[r]);
      ping[lr * 1024 + cw + lm] = (_Float16)h;
    }

    __syncthreads();   // all waves' LDS reads + global stores drained (vmcnt(0))
    if (t < TT - 1) {
      if (tid == 0) {
        // release: buffer_wbl2 (near-free: L2 kept clean by nt stores) +
        // vmcnt(0) + sc1 store. Publishes this WG's hbuf chunk.
        __hip_atomic_store(&flags[b * 16], t + 1,
                           __ATOMIC_RELEASE, __HIP_MEMORY_SCOPE_AGENT);
      }
      if (tid < 16) {     // lane i watches group-member i
        const int* fp = &flags[((g << 4) + tid) * 16];
        int spins = 0;
        // RELAXED fast path: no buffer_inv per spin (round-0's dominant cost).
        while (__hip_atomic_load(fp, __ATOMIC_RELAXED,
                                 __HIP_MEMORY_SCOPE_AGENT) < t + 1) {
          __builtin_amdgcn_s_sleep(1);
          if ((++spins & 63) == 0)   // liveness insurance: periodic inv
            (void)__hip_atomic_load(fp, __ATOMIC_ACQUIRE,
                                    __HIP_MEMORY_SCOPE_AGENT);
        }
      }
      // One acquire fence per step (wave 0 = the wave that observed the
      // flags): s_waitcnt + buffer_inv AFTER the last observation. Release
      // store -> relaxed observe -> acquire fence = synchronizes-with; all
      // waves' staging loads after the barrier see fresh hbuf (same CU: the
      // single inv covers the shared L1 and the XCD L2).
      if (w == 0)
        __builtin_amdgcn_fence(__ATOMIC_ACQUIRE, "agent");
      __syncthreads();
    }
  }
}

// ---------------------------------------------------------------- launcher
extern "C" void kernel_launch(void* const* d_in, const int* in_sizes, int n_in,
                              void* d_out, int out_size, void* d_ws, size_t ws_size,
                              hipStream_t stream) {
  const float* x   = (const float*)d_in[0];
  const float* h0  = (const float*)d_in[1];
  const float* Wx  = (const float*)d_in[2];
  const float* Wh  = (const float*)d_in[3];
  const float* bv  = (const float*)d_in[4];
  float* out = (float*)d_out;

  // ws layout: hbuf fp16 [2][8][16][1024] = 512 KB at 0; flags at 1 MB (8 KB)
  _Float16* hbuf = (_Float16*)d_ws;
  int* flags = (int*)((char*)d_ws + (1u << 20));

  hipMemsetAsync(flags, 0, 128 * 16 * sizeof(int), stream);

  gemm_xp<<<dim3((NB * TT / 128) * (HH / 128)), dim3(256), 0, stream>>>(x, Wx, bv, out);
  rnn_rec<<<dim3(128), dim3(256), 0, stream>>>(h0, Wh, out, hbuf, flags);
}